// Round 9
// baseline (156.635 us; speedup 1.0000x reference)
//
#include <hip/hip_runtime.h>

// MultiCenterLoss: loss = sum_{label==0} min_c ||f - c + eps||_2 / (count + 1e-5)
// ||f-c+eps||^2 = [f2 + 2*eps*fs + eps^2*D] + [c2 - 2*eps*cs] - 2*f.c
// min over c commutes with the per-sample constant: k_dist computes
// min_c (cc[c] - 2*f.c) via bf16 MFMA; per-sample constant ff from k_setup.
// Stream-ordered kernels (kernel boundary = cheap grid sync; cooperative
// grid.sync measured 10x slower in round 6 — cross-XCD spin).
// k_dist K-loop is double-buffered (T3-lite): one barrier per K-step,
// global->LDS staging of step kt+1 overlaps MFMA of step kt.
// Final reduction folded into k_dist's last-finishing block (done counter).

constexpr int N = 16384;
constexpr int D = 1024;
constexpr int C = 1024;
constexpr float EPS = 1e-6f;

constexpr int SB = 16;    // samples per work item
constexpr int CB = 128;   // centers per work item
constexpr int BK = 64;    // K elements per stage
constexpr int NKT = D / BK;  // 16 K-steps
constexpr int TPB = 256;
constexpr int DIST_GRID = 1024;

typedef __attribute__((ext_vector_type(8))) short bf16x8;
typedef __attribute__((ext_vector_type(4))) float f32x4;

// order-preserving float<->uint map (finite floats)
__device__ inline unsigned mapf(float f) {
  unsigned b = __float_as_uint(f);
  return (b & 0x80000000u) ? ~b : (b | 0x80000000u);
}
__device__ inline float unmapf(unsigned u) {
  return __uint_as_float((u & 0x80000000u) ? (u ^ 0x80000000u) : ~u);
}

// fp32 -> bf16 bits, round-to-nearest-even (inputs finite)
__device__ inline unsigned short f2bf(float x) {
  unsigned u = __float_as_uint(x);
  return (unsigned short)((u + 0x7FFFu + ((u >> 16) & 1u)) >> 16);
}

#define GLOAD_LDS16(gp, lp)                                        \
  __builtin_amdgcn_global_load_lds(                                \
      (const __attribute__((address_space(1))) void*)(gp),         \
      (__attribute__((address_space(3))) void*)(lp), 16, 0, 0)

// ---- k_setup (1024 blocks): block b owns center row b and samples [16b,16b+16)
//   * minmapped init + label==0 gather
//   * center row b: fp32 -> bf16 + cc[b] = sum(c^2) - 2*eps*sum(c)
//   * ff[slot] = sum(f^2) + 2*eps*sum(f) + eps^2*D for this block's selected rows
__global__ __launch_bounds__(TPB) void k_setup(
    const float* __restrict__ feat, const int* __restrict__ labels,
    const float* __restrict__ cent, unsigned* __restrict__ count,
    unsigned* __restrict__ sel, unsigned* __restrict__ minmapped,
    float* __restrict__ cc, float* __restrict__ ff,
    unsigned short* __restrict__ cent_bf) {
  __shared__ float red[8];
  __shared__ unsigned lrow[16], lslot[16];
  __shared__ int lcount;

  const int b = blockIdx.x, t = threadIdx.x;
  const int lane = t & 63, w = t >> 6;

  if (t == 0) lcount = 0;
  __syncthreads();

  if (t < 16) {
    int n = b * 16 + t;
    minmapped[n] = 0xFFFFFFFFu;
    if (labels[n] == 0) {
      unsigned slot = atomicAdd(count, 1u);
      sel[slot] = (unsigned)n;
      int li = atomicAdd(&lcount, 1);
      lrow[li] = (unsigned)n;
      lslot[li] = slot;
    }
  }

  // center row b: convert + constant
  {
    const float* row = cent + (size_t)b * D;
    float4 v = *(const float4*)(row + t * 4);
    *(short4*)(cent_bf + (size_t)b * D + t * 4) =
        make_short4((short)f2bf(v.x), (short)f2bf(v.y), (short)f2bf(v.z),
                    (short)f2bf(v.w));
    float s1 = v.x + v.y + v.z + v.w;
    float s2 = v.x * v.x + v.y * v.y + v.z * v.z + v.w * v.w;
#pragma unroll
    for (int off = 32; off; off >>= 1) {
      s1 += __shfl_down(s1, off);
      s2 += __shfl_down(s2, off);
    }
    if (lane == 0) { red[w] = s1; red[4 + w] = s2; }
    __syncthreads();
    if (t == 0) {
      float a1 = red[0] + red[1] + red[2] + red[3];
      float a2 = red[4] + red[5] + red[6] + red[7];
      cc[b] = a2 - 2.0f * EPS * a1;
    }
  }

  // ff for this block's selected rows (block-cooperative, ~1.6 rows avg)
  const int nl = lcount;
  for (int i = 0; i < nl; ++i) {
    __syncthreads();  // red reuse
    const float* row = feat + (size_t)lrow[i] * D;
    float4 v = *(const float4*)(row + t * 4);
    float s1 = v.x + v.y + v.z + v.w;
    float s2 = v.x * v.x + v.y * v.y + v.z * v.z + v.w * v.w;
#pragma unroll
    for (int off = 32; off; off >>= 1) {
      s1 += __shfl_down(s1, off);
      s2 += __shfl_down(s2, off);
    }
    if (lane == 0) { red[w] = s1; red[4 + w] = s2; }
    __syncthreads();
    if (t == 0) {
      float a1 = red[0] + red[1] + red[2] + red[3];
      float a2 = red[4] + red[5] + red[6] + red[7];
      ff[lslot[i]] = a2 + 2.0f * EPS * a1 + EPS * EPS * (float)D;
    }
  }
}

// ---- k_dist (1024 blocks, grid-stride): minmapped[s] min= (cc[c] - 2*f.c);
// last finishing block reduces loss and writes out.
// 16 samples x 128 centers per item, 4 waves (wave w owns centers [32w,32w+32)).
// [rows][64] bf16 LDS tiles, 16B-chunk XOR swizzle (j ^= row&7), DOUBLE-buffered:
// C-tile via global_load_lds (linear dest, inverse-swizzled global source),
// F-tile reg-staged fp32 -> bf16 -> swizzled ds_write.
__global__ __launch_bounds__(TPB) void k_dist(
    const float* __restrict__ feat, const unsigned short* __restrict__ cent_bf,
    const float* __restrict__ cc, const unsigned* __restrict__ count,
    const unsigned* __restrict__ sel, unsigned* __restrict__ minmapped,
    const float* __restrict__ ff, unsigned* __restrict__ done,
    float* __restrict__ out) {
  __shared__ __align__(16) unsigned short Cb[2][CB * BK];  // 2 x 16 KB
  __shared__ __align__(16) unsigned short Fb[2][SB * BK];  // 2 x 2 KB
  __shared__ unsigned rows_s[SB];
  __shared__ float red[4];
  __shared__ unsigned amlast;

  const unsigned cnt = *count;
  const unsigned nwork = ((cnt + SB - 1) / SB) * (C / CB);

  const int t = threadIdx.x;
  const int lane = t & 63, w = t >> 6;

  // F staging geometry: thread t -> sample s = t>>4, k4 = (t&15)*4
  const int fs_ = t >> 4;
  const int fk4 = (t & 15) * 4;
  const int fj = fk4 >> 3, fhalf = (fk4 >> 2) & 1;
  const int foff = fs_ * BK + ((fj ^ (fs_ & 7)) << 3) + (fhalf << 2);
  const int arow = lane & 15, kg = lane >> 4;
  const int c0 = w * 32 + (lane & 15), c1 = c0 + 16;

  for (unsigned wk = blockIdx.x; wk < nwork; wk += DIST_GRID) {
    const unsigned sbase = (wk >> 3) * SB;
    const unsigned cbase = (wk & 7) * CB;

    if (t < SB) rows_s[t] = sel[min(sbase + (unsigned)t, cnt - 1u)];
    __syncthreads();

    const float* fsrc = feat + (size_t)rows_s[fs_] * D + fk4;
    f32x4 acc0 = {0.f, 0.f, 0.f, 0.f}, acc1 = {0.f, 0.f, 0.f, 0.f};

    // stage K-step kt into buffer bb (C via gload_lds, F via reg+cvt)
    auto stage = [&](int kt, int bb) {
      const int kbase = kt * BK;
#pragma unroll
      for (int u = 0; u < 4; ++u) {
        int chunk = (w * 4 + u) * 64 + lane;
        int r = chunk >> 3, j = chunk & 7;
        int jsrc = j ^ (r & 7);
        const unsigned short* src =
            cent_bf + (size_t)(cbase + r) * D + kbase + jsrc * 8;
        GLOAD_LDS16(src, &Cb[bb][chunk * 8]);
      }
      float4 v = *(const float4*)(fsrc + kbase);
      *(short4*)&Fb[bb][foff] = make_short4((short)f2bf(v.x), (short)f2bf(v.y),
                                            (short)f2bf(v.z), (short)f2bf(v.w));
    };

    stage(0, 0);
    __syncthreads();

    for (int kt = 0; kt < NKT; ++kt) {
      const int cur = kt & 1;
      if (kt + 1 < NKT) stage(kt + 1, cur ^ 1);  // prefetch overlaps MFMA
#pragma unroll
      for (int ks = 0; ks < 2; ++ks) {
        int jj = (ks << 2) + kg;
        bf16x8 a =
            *(const bf16x8*)&Fb[cur][arow * BK + ((jj ^ (arow & 7)) << 3)];
        bf16x8 b0 =
            *(const bf16x8*)&Cb[cur][c0 * BK + ((jj ^ (c0 & 7)) << 3)];
        bf16x8 b1 =
            *(const bf16x8*)&Cb[cur][c1 * BK + ((jj ^ (c1 & 7)) << 3)];
        acc0 = __builtin_amdgcn_mfma_f32_16x16x32_bf16(a, b0, acc0, 0, 0, 0);
        acc1 = __builtin_amdgcn_mfma_f32_16x16x32_bf16(a, b1, acc1, 0, 0, 0);
      }
      __syncthreads();  // drains vmcnt (prefetch landed) + lgkm; one/K-step
    }

    // epilogue: cand = cc[c] - 2*dot; C/D layout: col=lane&15, row=(lane>>4)*4+reg
    float ccv0 = cc[cbase + c0];
    float ccv1 = cc[cbase + c1];
#pragma unroll
    for (int reg = 0; reg < 4; ++reg) {
      float v = fminf(ccv0 - 2.0f * acc0[reg], ccv1 - 2.0f * acc1[reg]);
#pragma unroll
      for (int off = 1; off < 16; off <<= 1) v = fminf(v, __shfl_xor(v, off));
      if ((lane & 15) == 0) {
        unsigned sidx = sbase + (unsigned)((lane >> 4) * 4 + reg);
        if (sidx < cnt) atomicMin(&minmapped[sidx], mapf(v));
      }
    }
    __syncthreads();  // protect rows_s/tiles before next work item
  }

  // ---- last-finishing block: loss = sum sqrt(max(ff + min, 0)) / (cnt+1e-5)
  if (t == 0) {
    __threadfence();
    amlast = (atomicAdd(done, 1u) == (unsigned)gridDim.x - 1u) ? 1u : 0u;
  }
  __syncthreads();
  if (amlast) {
    float s = 0.f;
    for (unsigned i = (unsigned)t; i < cnt; i += TPB) {
      // minmapped written by other blocks THIS kernel -> device-scope read;
      // ff written by k_setup (kernel boundary) -> plain load ok
      float sq = ff[i] + unmapf(atomicAdd(&minmapped[i], 0u));
      s += sqrtf(fmaxf(sq, 0.0f));
    }
#pragma unroll
    for (int off = 32; off; off >>= 1) s += __shfl_down(s, off);
    if (lane == 0) red[w] = s;
    __syncthreads();
    if (t == 0) {
      float total = red[0] + red[1] + red[2] + red[3];
      out[0] = total / ((float)cnt + 1e-5f);
    }
  }
}

extern "C" void kernel_launch(void* const* d_in, const int* in_sizes, int n_in,
                              void* d_out, int out_size, void* d_ws, size_t ws_size,
                              hipStream_t stream) {
  const float* feat = (const float*)d_in[0];
  const int* labels = (const int*)d_in[1];
  const float* cent = (const float*)d_in[2];
  float* out = (float*)d_out;

  char* ws = (char*)d_ws;
  unsigned* count = (unsigned*)ws;                              // @0
  unsigned* done = (unsigned*)(ws + 8);                         // @8
  unsigned* minmapped = (unsigned*)(ws + 16);                   // N u32
  unsigned* sel = (unsigned*)(ws + 16 + 4 * (size_t)N);         // N u32
  float* cc = (float*)(ws + 16 + 8 * (size_t)N);                // C f32
  float* ff = (float*)(ws + 16 + 8 * (size_t)N + 4 * (size_t)C);  // N f32
  unsigned short* cent_bf =
      (unsigned short*)(ws + 16 + 12 * (size_t)N + 4 * (size_t)C);  // C*D bf16

  hipMemsetAsync(d_ws, 0, 16, stream);

  k_setup<<<1024, TPB, 0, stream>>>(feat, labels, cent, count, sel, minmapped,
                                    cc, ff, cent_bf);
  k_dist<<<DIST_GRID, TPB, 0, stream>>>(feat, cent_bf, cc, count, sel,
                                        minmapped, ff, done, out);
}